// Round 5
// baseline (416.053 us; speedup 1.0000x reference)
//
#include <hip/hip_runtime.h>
#include <hip/hip_bf16.h>
#include <cstdint>

#define BF __hip_bfloat16

typedef __bf16 v8bf __attribute__((ext_vector_type(8)));
typedef float  v4f  __attribute__((ext_vector_type(4)));

__device__ __forceinline__ float tof(BF v) { return __bfloat162float(v); }
__device__ __forceinline__ BF    tob(float v) { return __float2bfloat16(v); }
__device__ __forceinline__ float ldf(float v) { return v; }
__device__ __forceinline__ float ldf(BF v) { return tof(v); }
__device__ __forceinline__ void stv(float* p, float v) { *p = v; }
__device__ __forceinline__ void stv(BF* p, float v) { *p = tob(v); }

__device__ __forceinline__ v4f mfma16(v8bf a, v8bf b, v4f c) {
  return __builtin_amdgcn_mfma_f32_16x16x32_bf16(a, b, c, 0, 0, 0);
}

__device__ __forceinline__ void async16(const BF* g, BF* l) {
  __builtin_amdgcn_global_load_lds((const __attribute__((address_space(1))) void*)g,
                                   (__attribute__((address_space(3))) void*)l, 16, 0, 0);
}

// ------------- transpose+cast: in fp32 [R][C] -> out bf16 [C][R] -------------
__global__ __launch_bounds__(256) void transpose_k(const float* __restrict__ in,
                                                   BF* __restrict__ out, int R, int C) {
  __shared__ BF t[64][65];
  int tid = threadIdx.x;
  int c0 = blockIdx.x * 64, r0 = blockIdx.y * 64;
#pragma unroll
  for (int i = 0; i < 16; ++i) {
    int idx = i * 256 + tid;
    int rr = idx >> 6, cc = idx & 63;
    t[rr][cc] = tob(in[(size_t)(r0 + rr) * C + c0 + cc]);
  }
  __syncthreads();
#pragma unroll
  for (int i = 0; i < 16; ++i) {
    int idx = i * 256 + tid;
    int rr = idx >> 6, cc = idx & 63;
    out[(size_t)(c0 + rr) * R + r0 + cc] = t[cc][rr];
  }
}

// ---- fused prep (big path): 4 weight transposes + ln1, one launch ----
// blocks [0,432) c_attn_w 36x12 | [432,576) c_proj_w 12x12 |
// [576,1152) fc_w 48x12 | [1152,1728) mproj_w 12x48 | [1728,9920) ln1 rows
__global__ __launch_bounds__(256) void prep_k(
    const float* __restrict__ caw, BF* __restrict__ oca,
    const float* __restrict__ pw,  BF* __restrict__ opj,
    const float* __restrict__ fw,  BF* __restrict__ ofc,
    const float* __restrict__ mw,  BF* __restrict__ omp,
    const float* __restrict__ x, const float* __restrict__ lw,
    const float* __restrict__ lb, BF* __restrict__ y) {
  __shared__ BF t[64][65];
  __shared__ float rs[4][2];
  const int bid = blockIdx.x;
  const int tid = threadIdx.x;
  if (bid < 1728) {
    const float* in; BF* out; int R, C, bx, by;
    if (bid < 432)       { in = caw; out = oca; R = 768;  C = 2304; bx = bid % 36; by = bid / 36; }
    else if (bid < 576)  { int i = bid - 432;  in = pw; out = opj; R = 768;  C = 768;  bx = i % 12; by = i / 12; }
    else if (bid < 1152) { int i = bid - 576;  in = fw; out = ofc; R = 768;  C = 3072; bx = i % 48; by = i / 48; }
    else                 { int i = bid - 1152; in = mw; out = omp; R = 3072; C = 768;  bx = i % 12; by = i / 12; }
    int c0 = bx * 64, r0 = by * 64;
#pragma unroll
    for (int i = 0; i < 16; ++i) {
      int idx = i * 256 + tid;
      int rr = idx >> 6, cc = idx & 63;
      t[rr][cc] = tob(in[(size_t)(r0 + rr) * C + c0 + cc]);
    }
    __syncthreads();
#pragma unroll
    for (int i = 0; i < 16; ++i) {
      int idx = i * 256 + tid;
      int rr = idx >> 6, cc = idx & 63;
      out[(size_t)(c0 + rr) * R + r0 + cc] = t[cc][rr];
    }
  } else {
    int row = bid - 1728;
    const float* xr = x + (size_t)row * 768;
    float v0 = xr[tid], v1 = xr[tid + 256], v2 = xr[tid + 512];
    float s1 = v0 + v1 + v2;
    float s2 = v0 * v0 + v1 * v1 + v2 * v2;
#pragma unroll
    for (int m = 32; m; m >>= 1) { s1 += __shfl_xor(s1, m); s2 += __shfl_xor(s2, m); }
    int wv = tid >> 6;
    if ((tid & 63) == 0) { rs[wv][0] = s1; rs[wv][1] = s2; }
    __syncthreads();
    s1 = rs[0][0] + rs[1][0] + rs[2][0] + rs[3][0];
    s2 = rs[0][1] + rs[1][1] + rs[2][1] + rs[3][1];
    float mean = s1 * (1.0f / 768.0f);
    float var = fmaxf((s2 - s1 * mean) * (1.0f / 767.0f), 0.0f);
    float rstd = rsqrtf(var + 1e-5f);
    BF* yr = y + (size_t)row * 768;
    yr[tid]       = tob((v0 - mean) * rstd * lw[tid]       + lb[tid]);
    yr[tid + 256] = tob((v1 - mean) * rstd * lw[tid + 256] + lb[tid + 256]);
    yr[tid + 512] = tob((v2 - mean) * rstd * lw[tid + 512] + lb[tid + 512]);
  }
}

// ------------- v-transpose: qkv v-part (bf16) -> vT[bh*64+d][t] -------------
__global__ __launch_bounds__(256) void vtrans_k(const BF* __restrict__ qkv,
                                                BF* __restrict__ vT) {
  __shared__ BF t[64][65];
  int tid = threadIdx.x;
  int t0 = blockIdx.x * 64;
  int bh = blockIdx.y;
  int b = bh / 12, h = bh % 12;
  const BF* src = qkv + (size_t)(b * 2048 + t0) * 2304 + 1536 + h * 64;
#pragma unroll
  for (int i = 0; i < 16; ++i) {
    int idx = i * 256 + tid;
    int rr = idx >> 6, cc = idx & 63;
    t[rr][cc] = src[(size_t)rr * 2304 + cc];
  }
  __syncthreads();
  BF* dst = vT + (size_t)bh * 64 * 2048 + t0;
#pragma unroll
  for (int i = 0; i < 16; ++i) {
    int idx = i * 256 + tid;
    int rr = idx >> 6, cc = idx & 63;
    dst[(size_t)rr * 2048 + cc] = t[cc][rr];
  }
}

// ------- layernorm (ddof=1), row per block; TX = float (x) or BF (x2) -------
template <typename TX>
__global__ __launch_bounds__(256) void ln_k(const TX* __restrict__ x,
                                            const float* __restrict__ w,
                                            const float* __restrict__ bia,
                                            BF* __restrict__ y) {
  int row = blockIdx.x, tid = threadIdx.x;
  const TX* xr = x + (size_t)row * 768;
  float v0 = ldf(xr[tid]), v1 = ldf(xr[tid + 256]), v2 = ldf(xr[tid + 512]);
  float s1 = v0 + v1 + v2;
  float s2 = v0 * v0 + v1 * v1 + v2 * v2;
#pragma unroll
  for (int m = 32; m; m >>= 1) { s1 += __shfl_xor(s1, m); s2 += __shfl_xor(s2, m); }
  __shared__ float rs[4][2];
  int wv = tid >> 6;
  if ((tid & 63) == 0) { rs[wv][0] = s1; rs[wv][1] = s2; }
  __syncthreads();
  s1 = rs[0][0] + rs[1][0] + rs[2][0] + rs[3][0];
  s2 = rs[0][1] + rs[1][1] + rs[2][1] + rs[3][1];
  float mean = s1 * (1.0f / 768.0f);
  float var = fmaxf((s2 - s1 * mean) * (1.0f / 767.0f), 0.0f);
  float rstd = rsqrtf(var + 1e-5f);
  BF* yr = y + (size_t)row * 768;
  yr[tid]       = tob((v0 - mean) * rstd * w[tid]       + bia[tid]);
  yr[tid + 256] = tob((v1 - mean) * rstd * w[tid + 256] + bia[tid + 256]);
  yr[tid + 512] = tob((v2 - mean) * rstd * w[tid + 512] + bia[tid + 512]);
}

__device__ __forceinline__ float gelu_f(float x) {
  float u = 0.7978845608028654f * (x + 0.044715f * x * x * x);
  float e = exp2f(2.8853900817779268f * u);          // e^{2u}
  return 0.5f * x * (1.0f + (1.0f - 2.0f / (e + 1.0f)));
}

// GEMM 2-phase (proven R2): BM=128, BK=64, dbuf, XOR swizzle, setprio.
template <int BN, int ACT, bool RESID, typename TR, typename TO>
__global__ __launch_bounds__(256) void gemm_sm_k(
    const BF* __restrict__ A, const BF* __restrict__ Bt, const float* __restrict__ bias,
    const TR* __restrict__ resid, TO* __restrict__ out, int M, int N, int K) {
  constexpr int NW = BN / 32;
  __shared__ __align__(16) BF As[2][128 * 64];
  __shared__ __align__(16) BF Bs[2][BN * 64];
  const int tid = threadIdx.x;
  const int w = tid >> 6, lane = tid & 63;
  const int quad = lane >> 4, l16 = lane & 15;
  const int gx = gridDim.x;
  const int nwg = gx * gridDim.y;
  const int lid = blockIdx.y * gx + blockIdx.x;
  const int swz = (lid & 7) * (nwg >> 3) + (lid >> 3);
  const int m0 = (swz / gx) * 128, n0 = (swz % gx) * BN;
  const int wm = (w >> 1) * 64, wn = (w & 1) * (BN / 2);
  const int sr = lane >> 3;
  const int sc = ((lane & 7) ^ sr) * 8;

  v4f acc[4][NW];
#pragma unroll
  for (int i = 0; i < 4; ++i)
#pragma unroll
    for (int j = 0; j < NW; ++j) acc[i][j] = (v4f){0.f, 0.f, 0.f, 0.f};

  auto stage = [&](int bsel, int k0) {
#pragma unroll
    for (int i = 0; i < 4; ++i) {
      int r0 = w * 32 + i * 8;
      async16(A + (size_t)(m0 + r0 + sr) * K + k0 + sc, &As[bsel][r0 * 64]);
    }
    if (BN == 128) {
#pragma unroll
      for (int i = 0; i < 4; ++i) {
        int r0 = w * 32 + i * 8;
        async16(Bt + (size_t)(n0 + r0 + sr) * K + k0 + sc, &Bs[bsel][r0 * 64]);
      }
    } else {
#pragma unroll
      for (int i = 0; i < 2; ++i) {
        int r0 = w * 16 + i * 8;
        async16(Bt + (size_t)(n0 + r0 + sr) * K + k0 + sc, &Bs[bsel][r0 * 64]);
      }
    }
  };

  const int nkt = K >> 6;
  stage(0, 0);
  __syncthreads();
  for (int kt = 0; kt < nkt; ++kt) {
    const int cur = kt & 1;
    if (kt + 1 < nkt) stage(cur ^ 1, (kt + 1) << 6);
#pragma unroll
    for (int kk = 0; kk < 2; ++kk) {
      v8bf af[4], bfv[NW];
#pragma unroll
      for (int mi = 0; mi < 4; ++mi) {
        int row = wm + mi * 16 + l16;
        af[mi] = *(const v8bf*)&As[cur][row * 64 + (((kk * 4 + quad) ^ (row & 7)) * 8)];
      }
#pragma unroll
      for (int nj = 0; nj < NW; ++nj) {
        int row = wn + nj * 16 + l16;
        bfv[nj] = *(const v8bf*)&Bs[cur][row * 64 + (((kk * 4 + quad) ^ (row & 7)) * 8)];
      }
      __builtin_amdgcn_s_setprio(1);
#pragma unroll
      for (int mi = 0; mi < 4; ++mi)
#pragma unroll
        for (int nj = 0; nj < NW; ++nj)
          acc[mi][nj] = mfma16(af[mi], bfv[nj], acc[mi][nj]);
      __builtin_amdgcn_s_setprio(0);
    }
    __syncthreads();
  }

#pragma unroll
  for (int nj = 0; nj < NW; ++nj) {
    int col = n0 + wn + nj * 16 + l16;
    float bv = bias[col];
#pragma unroll
    for (int mi = 0; mi < 4; ++mi) {
      v4f c = acc[mi][nj];
#pragma unroll
      for (int r = 0; r < 4; ++r) {
        int row = m0 + wm + mi * 16 + quad * 4 + r;
        float v = c[r] + bv;
        if (RESID) v += ldf(resid[(size_t)row * N + col]);
        if (ACT == 1) v = gelu_f(v);
        stv(&out[(size_t)row * N + col], v);
      }
    }
  }
}

// GEMM v5: BM=128, BN=64, BK=64, TRIPLE-buffered (72 KB -> 2 blocks/CU),
// counted vmcnt(6): tile t+2 issued at top of iter t, waited a FULL
// iteration later (never a hot drain); one barrier per K-tile; XOR-swizzled
// LDS via pre-swizzled source; setprio on MFMA; XCD chunk swizzle.
template <int ACT, bool RESID, typename TR, typename TO>
__global__ __launch_bounds__(256) void gemm3_k(
    const BF* __restrict__ A, const BF* __restrict__ Bt, const float* __restrict__ bias,
    const TR* __restrict__ resid, TO* __restrict__ out, int M, int N, int K) {
  __shared__ __align__(16) BF As[3][128 * 64];
  __shared__ __align__(16) BF Bs[3][64 * 64];
  const int tid = threadIdx.x;
  const int w = tid >> 6, lane = tid & 63;
  const int quad = lane >> 4, l16 = lane & 15;
  const int gx = gridDim.x;
  const int nwg = gx * gridDim.y;
  const int lid = blockIdx.y * gx + blockIdx.x;
  const int swz = (lid & 7) * (nwg >> 3) + (lid >> 3);
  const int m0 = (swz / gx) * 128, n0 = (swz % gx) * 64;
  const int wm = (w >> 1) * 64, wn = (w & 1) * 32;
  const int sr = lane >> 3;
  const int sc = ((lane & 7) ^ sr) * 8;

  v4f acc[4][2];
#pragma unroll
  for (int i = 0; i < 4; ++i)
#pragma unroll
    for (int j = 0; j < 2; ++j) acc[i][j] = (v4f){0.f, 0.f, 0.f, 0.f};

  // 6 async16 per lane per tile (4 A + 2 B): vmcnt counts in units of 6
  auto stage = [&](int bsel, int kt) {
    const int k0 = kt << 6;
#pragma unroll
    for (int i = 0; i < 4; ++i) {
      int r0 = w * 32 + i * 8;
      async16(A + (size_t)(m0 + r0 + sr) * K + k0 + sc, &As[bsel][r0 * 64]);
    }
#pragma unroll
    for (int i = 0; i < 2; ++i) {
      int r0 = w * 16 + i * 8;
      async16(Bt + (size_t)(n0 + r0 + sr) * K + k0 + sc, &Bs[bsel][r0 * 64]);
    }
  };

  const int nkt = K >> 6;
  stage(0, 0);
  stage(1, 1);
  asm volatile("s_waitcnt vmcnt(6)" ::: "memory");  // tile 0 landed (per wave)
  __builtin_amdgcn_s_barrier();
  asm volatile("" ::: "memory");

  for (int kt = 0; kt < nkt; ++kt) {
    if (kt + 2 < nkt) stage((kt + 2) % 3, kt + 2);  // waited a full iter later
    const BF* Ab = As[kt % 3];
    const BF* Bb = Bs[kt % 3];
#pragma unroll
    for (int kk = 0; kk < 2; ++kk) {
      v8bf af[4], bfv[2];
#pragma unroll
      for (int mi = 0; mi < 4; ++mi) {
        int row = wm + mi * 16 + l16;
        af[mi] = *(const v8bf*)&Ab[row * 64 + (((kk * 4 + quad) ^ (row & 7)) * 8)];
      }
#pragma unroll
      for (int nj = 0; nj < 2; ++nj) {
        int row = wn + nj * 16 + l16;
        bfv[nj] = *(const v8bf*)&Bb[row * 64 + (((kk * 4 + quad) ^ (row & 7)) * 8)];
      }
      __builtin_amdgcn_s_setprio(1);
#pragma unroll
      for (int mi = 0; mi < 4; ++mi)
#pragma unroll
        for (int nj = 0; nj < 2; ++nj)
          acc[mi][nj] = mfma16(af[mi], bfv[nj], acc[mi][nj]);
      __builtin_amdgcn_s_setprio(0);
    }
    if (kt + 1 < nkt) {
      if (kt + 2 < nkt) asm volatile("s_waitcnt vmcnt(6)" ::: "memory");  // t+1 ready
      else              asm volatile("s_waitcnt vmcnt(0)" ::: "memory");  // tail drain
      __builtin_amdgcn_s_barrier();
      asm volatile("" ::: "memory");
    }
  }

#pragma unroll
  for (int nj = 0; nj < 2; ++nj) {
    int col = n0 + wn + nj * 16 + l16;
    float bv = bias[col];
#pragma unroll
    for (int mi = 0; mi < 4; ++mi) {
      v4f c = acc[mi][nj];
#pragma unroll
      for (int r = 0; r < 4; ++r) {
        int row = m0 + wm + mi * 16 + quad * 4 + r;
        float v = c[r] + bv;
        if (RESID) v += ldf(resid[(size_t)row * N + col]);
        if (ACT == 1) v = gelu_f(v);
        stv(&out[(size_t)row * N + col], v);
      }
    }
  }
}

// ---- flash attention v4: 64 q-rows/block, 4 waves x 16-row frags,
// ---- K/V/P in XOR-swizzled stride-64 LDS (24 KB -> 6 blocks/CU),
// ---- 1536-block heavy-first 1D grid, register prefetch, setprio on MFMA,
// ---- no-max softmax, row-sum via ones-MFMA, full-tile fast path.
__global__ __launch_bounds__(256) void attn_k(const BF* __restrict__ qkv,
                                              const BF* __restrict__ vT,
                                              BF* __restrict__ out) {
  __shared__ __align__(16) BF Ks[64 * 64];
  __shared__ __align__(16) BF Vs[64 * 64];
  __shared__ __align__(16) BF Ps[4][16 * 64];
  const int tid = threadIdx.x;
  const int w = tid >> 6, lane = tid & 63;
  const int quad = lane >> 4, l16 = lane & 15;
  const int bid = blockIdx.x;
  const int qi = 31 - (bid / 48);               // heavy q-tiles dispatch first
  const int bh = bid % 48;
  const int b = bh / 12, h = bh % 12;
  const int q0 = qi * 64;
  const int qf = q0 + w * 16;                   // this wave's 16 q-rows
  BF* Pw = &Ps[w][0];
  const float L2E = 1.4426950408889634f;

  auto sz = [](int r, int c) { return (r << 6) + (c ^ ((r & 7) << 3)); };

  // Q fragment, pre-scaled by 1/8 (exact in bf16)
  const BF* qp = qkv + (size_t)(b * 2048 + qf + l16) * 2304 + h * 64;
  v8bf q0v = *(const v8bf*)(qp + quad * 8);
  v8bf q1v = *(const v8bf*)(qp + 32 + quad * 8);
#pragma unroll
  for (int i = 0; i < 8; ++i) {
    q0v[i] = (__bf16)(tof((BF)q0v[i]) * 0.125f);
    q1v[i] = (__bf16)(tof((BF)q1v[i]) * 0.125f);
  }
  v8bf ones;
#pragma unroll
  for (int i = 0; i < 8; ++i) ones[i] = (__bf16)1.0f;

  v4f O[4], S;
#pragma unroll
  for (int j = 0; j < 4; ++j) O[j] = (v4f){0.f, 0.f, 0.f, 0.f};
  S = (v4f){0.f, 0.f, 0.f, 0.f};

  const BF* kg = qkv + (size_t)b * 2048 * 2304 + 768 + h * 64;  // + t*2304
  const BF* vg = vT + (size_t)bh * 64 * 2048;                   // + d*2048 + t
  const int r0 = tid >> 3, c0 = (tid & 7) * 8;                  // rows 0..31
  const int r1 = r0 + 32;                                       // rows 32..63
  const int nIter = qi + 1;

  // prefetch tile 0
  v8bf nk0 = *(const v8bf*)(kg + (size_t)r0 * 2304 + c0);
  v8bf nk1 = *(const v8bf*)(kg + (size_t)r1 * 2304 + c0);
  v8bf nv0 = *(const v8bf*)(vg + (size_t)r0 * 2048 + c0);
  v8bf nv1 = *(const v8bf*)(vg + (size_t)r1 * 2048 + c0);

  for (int t = 0; t < nIter; ++t) {
    const int kt0 = t * 64;
    __syncthreads();
    *(v8bf*)&Ks[sz(r0, c0)] = nk0;
    *(v8bf*)&Ks[sz(r1, c0)] = nk1;
    *(v8bf*)&Vs[sz(r0, c0)] = nv0;
    *(v8bf*)&Vs[sz(r1, c0)] = nv1;
    __syncthreads();
    if (t + 1 < nIter) {  // prefetch next tile during compute (uniform branch)
      const int kn = kt0 + 64;
      nk0 = *(const v8bf*)(kg + (size_t)(kn + r0) * 2304 + c0);
      nk1 = *(const v8bf*)(kg + (size_t)(kn + r1) * 2304 + c0);
      nv0 = *(const v8bf*)(vg + (size_t)r0 * 2048 + kn + c0);
      nv1 = *(const v8bf*)(vg + (size_t)r1 * 2048 + kn + c0);
    }
    v4f s[4];
    __builtin_amdgcn_s_setprio(1);
#pragma unroll
    for (int nt = 0; nt < 4; ++nt) {
      v8bf kf0 = *(const v8bf*)&Ks[sz(nt * 16 + l16, quad * 8)];
      v8bf kf1 = *(const v8bf*)&Ks[sz(nt * 16 + l16, 32 + quad * 8)];
      s[nt] = mfma16(q1v, kf1, mfma16(q0v, kf0, (v4f){0.f, 0.f, 0.f, 0.f}));
    }
    __builtin_amdgcn_s_setprio(0);
    if (t < qi) {  // fully unmasked tile (wave-uniform)
#pragma unroll
      for (int nt = 0; nt < 4; ++nt)
#pragma unroll
        for (int r = 0; r < 4; ++r)
          Pw[sz(quad * 4 + r, nt * 16 + l16)] = tob(exp2f(s[nt][r] * L2E));
    } else {       // diagonal tile: causal mask
#pragma unroll
      for (int nt = 0; nt < 4; ++nt) {
        int key = kt0 + nt * 16 + l16;
#pragma unroll
        for (int r = 0; r < 4; ++r) {
          int qrow = qf + quad * 4 + r;
          float p = (key <= qrow) ? exp2f(s[nt][r] * L2E) : 0.f;
          Pw[sz(quad * 4 + r, nt * 16 + l16)] = tob(p);
        }
      }
    }
    asm volatile("s_waitcnt lgkmcnt(0)" ::: "memory");
    v8bf p0 = *(const v8bf*)&Pw[sz(l16, quad * 8)];
    v8bf p1 = *(const v8bf*)&Pw[sz(l16, 32 + quad * 8)];
    __builtin_amdgcn_s_setprio(1);
#pragma unroll
    for (int j = 0; j < 4; ++j) {
      v8bf vf0 = *(const v8bf*)&Vs[sz(j * 16 + l16, quad * 8)];
      v8bf vf1 = *(const v8bf*)&Vs[sz(j * 16 + l16, 32 + quad * 8)];
      O[j] = mfma16(p1, vf1, mfma16(p0, vf0, O[j]));
    }
    S = mfma16(p1, ones, mfma16(p0, ones, S));
    __builtin_amdgcn_s_setprio(0);
  }

#pragma unroll
  for (int r = 0; r < 4; ++r) {
    float inv = 1.0f / S[r];
    int row = b * 2048 + qf + quad * 4 + r;
    BF* op = out + (size_t)row * 768 + h * 64 + l16;
#pragma unroll
    for (int j = 0; j < 4; ++j) op[j * 16] = tob(O[j][r] * inv);
  }
}

extern "C" void kernel_launch(void* const* d_in, const int* in_sizes, int n_in,
                              void* d_out, int out_size, void* d_ws, size_t ws_size,
                              hipStream_t stream) {
  const float* x        = (const float*)d_in[0];
  const float* ln1_w    = (const float*)d_in[1];
  const float* ln1_b    = (const float*)d_in[2];
  const float* c_attn_w = (const float*)d_in[3];
  const float* c_attn_b = (const float*)d_in[4];
  const float* c_proj_w = (const float*)d_in[5];
  const float* c_proj_b = (const float*)d_in[6];
  const float* ln2_w    = (const float*)d_in[7];
  const float* ln2_b    = (const float*)d_in[8];
  const float* fc_w     = (const float*)d_in[9];
  const float* fc_b     = (const float*)d_in[10];
  const float* mproj_w  = (const float*)d_in[11];
  const float* mproj_b  = (const float*)d_in[12];
  float* out = (float*)d_out;
  char* wsb = (char*)d_ws;
  dim3 blk(256);

  BF* vT = (BF*)((char*)d_out + 12582912);

  const size_t NEED_BIG = 89653248;
  if (ws_size >= NEED_BIG) {
    BF* qkv      = (BF*)(wsb);
    BF* hbuf     = (BF*)(wsb);
    BF* x2       = (BF*)(wsb + 50331648);
    BF* wT_attn  = (BF*)(wsb + 62914560);
    BF* wT_proj  = (BF*)(wsb + 66453504);
    BF* wT_fc    = (BF*)(wsb + 67633152);
    BF* wT_mproj = (BF*)(wsb + 72351744);
    BF* lnbuf    = (BF*)(wsb + 77070336);
    BF* attnout  = (BF*)d_out;

    prep_k<<<dim3(9920), blk, 0, stream>>>(c_attn_w, wT_attn, c_proj_w, wT_proj,
                                           fc_w, wT_fc, mproj_w, wT_mproj,
                                           x, ln1_w, ln1_b, lnbuf);
    gemm3_k<0, false, float, BF><<<dim3(36, 64), blk, 0, stream>>>(
        lnbuf, wT_attn, c_attn_b, (const float*)nullptr, qkv, 8192, 2304, 768);
    vtrans_k<<<dim3(32, 48), blk, 0, stream>>>(qkv, vT);
    attn_k<<<dim3(1536), blk, 0, stream>>>(qkv, vT, attnout);
    gemm3_k<0, true, float, BF><<<dim3(12, 64), blk, 0, stream>>>(
        attnout, wT_proj, c_proj_b, x, x2, 8192, 768, 768);
    ln_k<BF><<<8192, blk, 0, stream>>>(x2, ln2_w, ln2_b, lnbuf);
    gemm_sm_k<128, 1, false, float, BF><<<dim3(24, 64), blk, 0, stream>>>(
        lnbuf, wT_fc, fc_b, (const float*)nullptr, hbuf, 8192, 3072, 768);
    gemm3_k<0, true, BF, float><<<dim3(12, 64), blk, 0, stream>>>(
        hbuf, wT_mproj, mproj_b, x2, out, 8192, 768, 3072);
  } else {
    BF* ws       = (BF*)d_ws;
    BF* qkv      = ws;
    BF* attnout  = ws + (size_t)18874368;
    BF* wT_attn  = attnout;
    BF* x2       = ws;
    BF* wT_proj  = ws + (size_t)6291456;
    BF* wT_fc    = ws + (size_t)6881280;
    BF* wT_mproj = ws + (size_t)9240576;
    BF* hbuf     = ws + (size_t)11599872;
    BF* lnbuf    = (BF*)d_out;

    transpose_k<<<dim3(36, 12), blk, 0, stream>>>(c_attn_w, wT_attn, 768, 2304);
    ln_k<float><<<8192, blk, 0, stream>>>(x, ln1_w, ln1_b, lnbuf);
    gemm3_k<0, false, float, BF><<<dim3(36, 64), blk, 0, stream>>>(
        lnbuf, wT_attn, c_attn_b, (const float*)nullptr, qkv, 8192, 2304, 768);
    vtrans_k<<<dim3(32, 48), blk, 0, stream>>>(qkv, vT);
    attn_k<<<dim3(1536), blk, 0, stream>>>(qkv, vT, attnout);
    transpose_k<<<dim3(12, 12), blk, 0, stream>>>(c_proj_w, wT_proj, 768, 768);
    gemm3_k<0, true, float, BF><<<dim3(12, 64), blk, 0, stream>>>(
        attnout, wT_proj, c_proj_b, x, x2, 8192, 768, 768);
    ln_k<BF><<<8192, blk, 0, stream>>>(x2, ln2_w, ln2_b, lnbuf);
    transpose_k<<<dim3(48, 12), blk, 0, stream>>>(fc_w, wT_fc, 768, 3072);
    transpose_k<<<dim3(12, 48), blk, 0, stream>>>(mproj_w, wT_mproj, 3072, 768);
    for (int half = 1; half >= 0; --half) {
      size_t r0 = (size_t)half * 4096;
      gemm_sm_k<128, 1, false, float, BF><<<dim3(24, 32), blk, 0, stream>>>(
          lnbuf + r0 * 768, wT_fc, fc_b, (const float*)nullptr, hbuf, 4096, 3072, 768);
      gemm3_k<0, true, BF, float><<<dim3(12, 32), blk, 0, stream>>>(
          hbuf, wT_mproj, mproj_b, x2 + r0 * 768, out + r0 * 768, 4096, 768, 3072);
    }
  }
}

// Round 6
// 359.747 us; speedup vs baseline: 1.1565x; 1.1565x over previous
//
#include <hip/hip_runtime.h>
#include <hip/hip_bf16.h>
#include <cstdint>

#define BF __hip_bfloat16

typedef __bf16 v8bf __attribute__((ext_vector_type(8)));
typedef float  v4f  __attribute__((ext_vector_type(4)));

__device__ __forceinline__ float tof(BF v) { return __bfloat162float(v); }
__device__ __forceinline__ BF    tob(float v) { return __float2bfloat16(v); }
__device__ __forceinline__ float ldf(float v) { return v; }
__device__ __forceinline__ float ldf(BF v) { return tof(v); }
__device__ __forceinline__ void stv(float* p, float v) { *p = v; }
__device__ __forceinline__ void stv(BF* p, float v) { *p = tob(v); }

__device__ __forceinline__ v4f mfma16(v8bf a, v8bf b, v4f c) {
  return __builtin_amdgcn_mfma_f32_16x16x32_bf16(a, b, c, 0, 0, 0);
}

__device__ __forceinline__ void async16(const BF* g, BF* l) {
  __builtin_amdgcn_global_load_lds((const __attribute__((address_space(1))) void*)g,
                                   (__attribute__((address_space(3))) void*)l, 16, 0, 0);
}

// ------------- transpose+cast: in fp32 [R][C] -> out bf16 [C][R] -------------
__global__ __launch_bounds__(256) void transpose_k(const float* __restrict__ in,
                                                   BF* __restrict__ out, int R, int C) {
  __shared__ BF t[64][65];
  int tid = threadIdx.x;
  int c0 = blockIdx.x * 64, r0 = blockIdx.y * 64;
#pragma unroll
  for (int i = 0; i < 16; ++i) {
    int idx = i * 256 + tid;
    int rr = idx >> 6, cc = idx & 63;
    t[rr][cc] = tob(in[(size_t)(r0 + rr) * C + c0 + cc]);
  }
  __syncthreads();
#pragma unroll
  for (int i = 0; i < 16; ++i) {
    int idx = i * 256 + tid;
    int rr = idx >> 6, cc = idx & 63;
    out[(size_t)(c0 + rr) * R + r0 + cc] = t[cc][rr];
  }
}

// ---- fused prep (big path): 4 weight transposes + ln1, one launch ----
__global__ __launch_bounds__(256) void prep_k(
    const float* __restrict__ caw, BF* __restrict__ oca,
    const float* __restrict__ pw,  BF* __restrict__ opj,
    const float* __restrict__ fw,  BF* __restrict__ ofc,
    const float* __restrict__ mw,  BF* __restrict__ omp,
    const float* __restrict__ x, const float* __restrict__ lw,
    const float* __restrict__ lb, BF* __restrict__ y) {
  __shared__ BF t[64][65];
  __shared__ float rs[4][2];
  const int bid = blockIdx.x;
  const int tid = threadIdx.x;
  if (bid < 1728) {
    const float* in; BF* out; int R, C, bx, by;
    if (bid < 432)       { in = caw; out = oca; R = 768;  C = 2304; bx = bid % 36; by = bid / 36; }
    else if (bid < 576)  { int i = bid - 432;  in = pw; out = opj; R = 768;  C = 768;  bx = i % 12; by = i / 12; }
    else if (bid < 1152) { int i = bid - 576;  in = fw; out = ofc; R = 768;  C = 3072; bx = i % 48; by = i / 48; }
    else                 { int i = bid - 1152; in = mw; out = omp; R = 3072; C = 768;  bx = i % 12; by = i / 12; }
    int c0 = bx * 64, r0 = by * 64;
#pragma unroll
    for (int i = 0; i < 16; ++i) {
      int idx = i * 256 + tid;
      int rr = idx >> 6, cc = idx & 63;
      t[rr][cc] = tob(in[(size_t)(r0 + rr) * C + c0 + cc]);
    }
    __syncthreads();
#pragma unroll
    for (int i = 0; i < 16; ++i) {
      int idx = i * 256 + tid;
      int rr = idx >> 6, cc = idx & 63;
      out[(size_t)(c0 + rr) * R + r0 + cc] = t[cc][rr];
    }
  } else {
    int row = bid - 1728;
    const float* xr = x + (size_t)row * 768;
    float v0 = xr[tid], v1 = xr[tid + 256], v2 = xr[tid + 512];
    float s1 = v0 + v1 + v2;
    float s2 = v0 * v0 + v1 * v1 + v2 * v2;
#pragma unroll
    for (int m = 32; m; m >>= 1) { s1 += __shfl_xor(s1, m); s2 += __shfl_xor(s2, m); }
    int wv = tid >> 6;
    if ((tid & 63) == 0) { rs[wv][0] = s1; rs[wv][1] = s2; }
    __syncthreads();
    s1 = rs[0][0] + rs[1][0] + rs[2][0] + rs[3][0];
    s2 = rs[0][1] + rs[1][1] + rs[2][1] + rs[3][1];
    float mean = s1 * (1.0f / 768.0f);
    float var = fmaxf((s2 - s1 * mean) * (1.0f / 767.0f), 0.0f);
    float rstd = rsqrtf(var + 1e-5f);
    BF* yr = y + (size_t)row * 768;
    yr[tid]       = tob((v0 - mean) * rstd * lw[tid]       + lb[tid]);
    yr[tid + 256] = tob((v1 - mean) * rstd * lw[tid + 256] + lb[tid + 256]);
    yr[tid + 512] = tob((v2 - mean) * rstd * lw[tid + 512] + lb[tid + 512]);
  }
}

// ------------- v-transpose: qkv v-part (bf16) -> vT[bh*64+d][t] -------------
__global__ __launch_bounds__(256) void vtrans_k(const BF* __restrict__ qkv,
                                                BF* __restrict__ vT) {
  __shared__ BF t[64][65];
  int tid = threadIdx.x;
  int t0 = blockIdx.x * 64;
  int bh = blockIdx.y;
  int b = bh / 12, h = bh % 12;
  const BF* src = qkv + (size_t)(b * 2048 + t0) * 2304 + 1536 + h * 64;
#pragma unroll
  for (int i = 0; i < 16; ++i) {
    int idx = i * 256 + tid;
    int rr = idx >> 6, cc = idx & 63;
    t[rr][cc] = src[(size_t)rr * 2304 + cc];
  }
  __syncthreads();
  BF* dst = vT + (size_t)bh * 64 * 2048 + t0;
#pragma unroll
  for (int i = 0; i < 16; ++i) {
    int idx = i * 256 + tid;
    int rr = idx >> 6, cc = idx & 63;
    dst[(size_t)rr * 2048 + cc] = t[cc][rr];
  }
}

// ------- layernorm (ddof=1), row per block; TX = float (x) or BF (x2) -------
template <typename TX>
__global__ __launch_bounds__(256) void ln_k(const TX* __restrict__ x,
                                            const float* __restrict__ w,
                                            const float* __restrict__ bia,
                                            BF* __restrict__ y) {
  int row = blockIdx.x, tid = threadIdx.x;
  const TX* xr = x + (size_t)row * 768;
  float v0 = ldf(xr[tid]), v1 = ldf(xr[tid + 256]), v2 = ldf(xr[tid + 512]);
  float s1 = v0 + v1 + v2;
  float s2 = v0 * v0 + v1 * v1 + v2 * v2;
#pragma unroll
  for (int m = 32; m; m >>= 1) { s1 += __shfl_xor(s1, m); s2 += __shfl_xor(s2, m); }
  __shared__ float rs[4][2];
  int wv = tid >> 6;
  if ((tid & 63) == 0) { rs[wv][0] = s1; rs[wv][1] = s2; }
  __syncthreads();
  s1 = rs[0][0] + rs[1][0] + rs[2][0] + rs[3][0];
  s2 = rs[0][1] + rs[1][1] + rs[2][1] + rs[3][1];
  float mean = s1 * (1.0f / 768.0f);
  float var = fmaxf((s2 - s1 * mean) * (1.0f / 767.0f), 0.0f);
  float rstd = rsqrtf(var + 1e-5f);
  BF* yr = y + (size_t)row * 768;
  yr[tid]       = tob((v0 - mean) * rstd * w[tid]       + bia[tid]);
  yr[tid + 256] = tob((v1 - mean) * rstd * w[tid + 256] + bia[tid + 256]);
  yr[tid + 512] = tob((v2 - mean) * rstd * w[tid + 512] + bia[tid + 512]);
}

__device__ __forceinline__ float gelu_f(float x) {
  float u = 0.7978845608028654f * (x + 0.044715f * x * x * x);
  float e = exp2f(2.8853900817779268f * u);          // e^{2u}
  return 0.5f * x * (1.0f + (1.0f - 2.0f / (e + 1.0f)));
}

// GEMM 2-phase (proven R2): BM=128, BK=64, dbuf, XOR swizzle, setprio.
template <int BN, int ACT, bool RESID, typename TR, typename TO>
__global__ __launch_bounds__(256) void gemm_sm_k(
    const BF* __restrict__ A, const BF* __restrict__ Bt, const float* __restrict__ bias,
    const TR* __restrict__ resid, TO* __restrict__ out, int M, int N, int K) {
  constexpr int NW = BN / 32;
  __shared__ __align__(16) BF As[2][128 * 64];
  __shared__ __align__(16) BF Bs[2][BN * 64];
  const int tid = threadIdx.x;
  const int w = tid >> 6, lane = tid & 63;
  const int quad = lane >> 4, l16 = lane & 15;
  const int gx = gridDim.x;
  const int nwg = gx * gridDim.y;
  const int lid = blockIdx.y * gx + blockIdx.x;
  const int swz = (lid & 7) * (nwg >> 3) + (lid >> 3);
  const int m0 = (swz / gx) * 128, n0 = (swz % gx) * BN;
  const int wm = (w >> 1) * 64, wn = (w & 1) * (BN / 2);
  const int sr = lane >> 3;
  const int sc = ((lane & 7) ^ sr) * 8;

  v4f acc[4][NW];
#pragma unroll
  for (int i = 0; i < 4; ++i)
#pragma unroll
    for (int j = 0; j < NW; ++j) acc[i][j] = (v4f){0.f, 0.f, 0.f, 0.f};

  auto stage = [&](int bsel, int k0) {
#pragma unroll
    for (int i = 0; i < 4; ++i) {
      int r0 = w * 32 + i * 8;
      async16(A + (size_t)(m0 + r0 + sr) * K + k0 + sc, &As[bsel][r0 * 64]);
    }
    if (BN == 128) {
#pragma unroll
      for (int i = 0; i < 4; ++i) {
        int r0 = w * 32 + i * 8;
        async16(Bt + (size_t)(n0 + r0 + sr) * K + k0 + sc, &Bs[bsel][r0 * 64]);
      }
    } else {
#pragma unroll
      for (int i = 0; i < 2; ++i) {
        int r0 = w * 16 + i * 8;
        async16(Bt + (size_t)(n0 + r0 + sr) * K + k0 + sc, &Bs[bsel][r0 * 64]);
      }
    }
  };

  const int nkt = K >> 6;
  stage(0, 0);
  __syncthreads();
  for (int kt = 0; kt < nkt; ++kt) {
    const int cur = kt & 1;
    if (kt + 1 < nkt) stage(cur ^ 1, (kt + 1) << 6);
#pragma unroll
    for (int kk = 0; kk < 2; ++kk) {
      v8bf af[4], bfv[NW];
#pragma unroll
      for (int mi = 0; mi < 4; ++mi) {
        int row = wm + mi * 16 + l16;
        af[mi] = *(const v8bf*)&As[cur][row * 64 + (((kk * 4 + quad) ^ (row & 7)) * 8)];
      }
#pragma unroll
      for (int nj = 0; nj < NW; ++nj) {
        int row = wn + nj * 16 + l16;
        bfv[nj] = *(const v8bf*)&Bs[cur][row * 64 + (((kk * 4 + quad) ^ (row & 7)) * 8)];
      }
      __builtin_amdgcn_s_setprio(1);
#pragma unroll
      for (int mi = 0; mi < 4; ++mi)
#pragma unroll
        for (int nj = 0; nj < NW; ++nj)
          acc[mi][nj] = mfma16(af[mi], bfv[nj], acc[mi][nj]);
      __builtin_amdgcn_s_setprio(0);
    }
    __syncthreads();
  }

#pragma unroll
  for (int nj = 0; nj < NW; ++nj) {
    int col = n0 + wn + nj * 16 + l16;
    float bv = bias[col];
#pragma unroll
    for (int mi = 0; mi < 4; ++mi) {
      v4f c = acc[mi][nj];
#pragma unroll
      for (int r = 0; r < 4; ++r) {
        int row = m0 + wm + mi * 16 + quad * 4 + r;
        float v = c[r] + bv;
        if (RESID) v += ldf(resid[(size_t)row * N + col]);
        if (ACT == 1) v = gelu_f(v);
        stv(&out[(size_t)row * N + col], v);
      }
    }
  }
}

// GEMM probe: BM=64, BN=128, BK=64 — IDENTICAL loop structure to gemm_sm,
// but 48 KB LDS -> 3 blocks/CU (12 waves/CU) for stall hiding.
template <int ACT, bool RESID, typename TR, typename TO>
__global__ __launch_bounds__(256) void gemm64_k(
    const BF* __restrict__ A, const BF* __restrict__ Bt, const float* __restrict__ bias,
    const TR* __restrict__ resid, TO* __restrict__ out, int M, int N, int K) {
  __shared__ __align__(16) BF As[2][64 * 64];
  __shared__ __align__(16) BF Bs[2][128 * 64];
  const int tid = threadIdx.x;
  const int w = tid >> 6, lane = tid & 63;
  const int quad = lane >> 4, l16 = lane & 15;
  const int gx = gridDim.x;
  const int nwg = gx * gridDim.y;
  const int lid = blockIdx.y * gx + blockIdx.x;
  const int swz = (lid & 7) * (nwg >> 3) + (lid >> 3);
  const int m0 = (swz / gx) * 64, n0 = (swz % gx) * 128;
  const int wm = (w >> 1) * 32, wn = (w & 1) * 64;   // wave tile 32x64
  const int sr = lane >> 3;
  const int sc = ((lane & 7) ^ sr) * 8;

  v4f acc[2][4];
#pragma unroll
  for (int i = 0; i < 2; ++i)
#pragma unroll
    for (int j = 0; j < 4; ++j) acc[i][j] = (v4f){0.f, 0.f, 0.f, 0.f};

  auto stage = [&](int bsel, int k0) {
#pragma unroll
    for (int i = 0; i < 2; ++i) {                 // A: 64 rows
      int r0 = w * 16 + i * 8;
      async16(A + (size_t)(m0 + r0 + sr) * K + k0 + sc, &As[bsel][r0 * 64]);
    }
#pragma unroll
    for (int i = 0; i < 4; ++i) {                 // B: 128 rows
      int r0 = w * 32 + i * 8;
      async16(Bt + (size_t)(n0 + r0 + sr) * K + k0 + sc, &Bs[bsel][r0 * 64]);
    }
  };

  const int nkt = K >> 6;
  stage(0, 0);
  __syncthreads();
  for (int kt = 0; kt < nkt; ++kt) {
    const int cur = kt & 1;
    if (kt + 1 < nkt) stage(cur ^ 1, (kt + 1) << 6);
#pragma unroll
    for (int kk = 0; kk < 2; ++kk) {
      v8bf af[2], bfv[4];
#pragma unroll
      for (int mi = 0; mi < 2; ++mi) {
        int row = wm + mi * 16 + l16;
        af[mi] = *(const v8bf*)&As[cur][row * 64 + (((kk * 4 + quad) ^ (row & 7)) * 8)];
      }
#pragma unroll
      for (int nj = 0; nj < 4; ++nj) {
        int row = wn + nj * 16 + l16;
        bfv[nj] = *(const v8bf*)&Bs[cur][row * 64 + (((kk * 4 + quad) ^ (row & 7)) * 8)];
      }
      __builtin_amdgcn_s_setprio(1);
#pragma unroll
      for (int mi = 0; mi < 2; ++mi)
#pragma unroll
        for (int nj = 0; nj < 4; ++nj)
          acc[mi][nj] = mfma16(af[mi], bfv[nj], acc[mi][nj]);
      __builtin_amdgcn_s_setprio(0);
    }
    __syncthreads();
  }

#pragma unroll
  for (int nj = 0; nj < 4; ++nj) {
    int col = n0 + wn + nj * 16 + l16;
    float bv = bias[col];
#pragma unroll
    for (int mi = 0; mi < 2; ++mi) {
      v4f c = acc[mi][nj];
#pragma unroll
      for (int r = 0; r < 4; ++r) {
        int row = m0 + wm + mi * 16 + quad * 4 + r;
        float v = c[r] + bv;
        if (RESID) v += ldf(resid[(size_t)row * N + col]);
        if (ACT == 1) v = gelu_f(v);
        stv(&out[(size_t)row * N + col], v);
      }
    }
  }
}

// ---- flash attention v4: 64 q-rows/block, 4 waves x 16-row frags,
// ---- K/V/P in XOR-swizzled stride-64 LDS, heavy-first 1D grid,
// ---- register prefetch, setprio, no-max softmax, ones-MFMA row-sum.
__global__ __launch_bounds__(256) void attn_k(const BF* __restrict__ qkv,
                                              const BF* __restrict__ vT,
                                              BF* __restrict__ out) {
  __shared__ __align__(16) BF Ks[64 * 64];
  __shared__ __align__(16) BF Vs[64 * 64];
  __shared__ __align__(16) BF Ps[4][16 * 64];
  const int tid = threadIdx.x;
  const int w = tid >> 6, lane = tid & 63;
  const int quad = lane >> 4, l16 = lane & 15;
  const int bid = blockIdx.x;
  const int qi = 31 - (bid / 48);
  const int bh = bid % 48;
  const int b = bh / 12, h = bh % 12;
  const int q0 = qi * 64;
  const int qf = q0 + w * 16;
  BF* Pw = &Ps[w][0];
  const float L2E = 1.4426950408889634f;

  auto sz = [](int r, int c) { return (r << 6) + (c ^ ((r & 7) << 3)); };

  const BF* qp = qkv + (size_t)(b * 2048 + qf + l16) * 2304 + h * 64;
  v8bf q0v = *(const v8bf*)(qp + quad * 8);
  v8bf q1v = *(const v8bf*)(qp + 32 + quad * 8);
#pragma unroll
  for (int i = 0; i < 8; ++i) {
    q0v[i] = (__bf16)(tof((BF)q0v[i]) * 0.125f);
    q1v[i] = (__bf16)(tof((BF)q1v[i]) * 0.125f);
  }
  v8bf ones;
#pragma unroll
  for (int i = 0; i < 8; ++i) ones[i] = (__bf16)1.0f;

  v4f O[4], S;
#pragma unroll
  for (int j = 0; j < 4; ++j) O[j] = (v4f){0.f, 0.f, 0.f, 0.f};
  S = (v4f){0.f, 0.f, 0.f, 0.f};

  const BF* kg = qkv + (size_t)b * 2048 * 2304 + 768 + h * 64;
  const BF* vg = vT + (size_t)bh * 64 * 2048;
  const int r0 = tid >> 3, c0 = (tid & 7) * 8;
  const int r1 = r0 + 32;
  const int nIter = qi + 1;

  v8bf nk0 = *(const v8bf*)(kg + (size_t)r0 * 2304 + c0);
  v8bf nk1 = *(const v8bf*)(kg + (size_t)r1 * 2304 + c0);
  v8bf nv0 = *(const v8bf*)(vg + (size_t)r0 * 2048 + c0);
  v8bf nv1 = *(const v8bf*)(vg + (size_t)r1 * 2048 + c0);

  for (int t = 0; t < nIter; ++t) {
    const int kt0 = t * 64;
    __syncthreads();
    *(v8bf*)&Ks[sz(r0, c0)] = nk0;
    *(v8bf*)&Ks[sz(r1, c0)] = nk1;
    *(v8bf*)&Vs[sz(r0, c0)] = nv0;
    *(v8bf*)&Vs[sz(r1, c0)] = nv1;
    __syncthreads();
    if (t + 1 < nIter) {
      const int kn = kt0 + 64;
      nk0 = *(const v8bf*)(kg + (size_t)(kn + r0) * 2304 + c0);
      nk1 = *(const v8bf*)(kg + (size_t)(kn + r1) * 2304 + c0);
      nv0 = *(const v8bf*)(vg + (size_t)r0 * 2048 + kn + c0);
      nv1 = *(const v8bf*)(vg + (size_t)r1 * 2048 + kn + c0);
    }
    v4f s[4];
    __builtin_amdgcn_s_setprio(1);
#pragma unroll
    for (int nt = 0; nt < 4; ++nt) {
      v8bf kf0 = *(const v8bf*)&Ks[sz(nt * 16 + l16, quad * 8)];
      v8bf kf1 = *(const v8bf*)&Ks[sz(nt * 16 + l16, 32 + quad * 8)];
      s[nt] = mfma16(q1v, kf1, mfma16(q0v, kf0, (v4f){0.f, 0.f, 0.f, 0.f}));
    }
    __builtin_amdgcn_s_setprio(0);
    if (t < qi) {
#pragma unroll
      for (int nt = 0; nt < 4; ++nt)
#pragma unroll
        for (int r = 0; r < 4; ++r)
          Pw[sz(quad * 4 + r, nt * 16 + l16)] = tob(exp2f(s[nt][r] * L2E));
    } else {
#pragma unroll
      for (int nt = 0; nt < 4; ++nt) {
        int key = kt0 + nt * 16 + l16;
#pragma unroll
        for (int r = 0; r < 4; ++r) {
          int qrow = qf + quad * 4 + r;
          float p = (key <= qrow) ? exp2f(s[nt][r] * L2E) : 0.f;
          Pw[sz(quad * 4 + r, nt * 16 + l16)] = tob(p);
        }
      }
    }
    asm volatile("s_waitcnt lgkmcnt(0)" ::: "memory");
    v8bf p0 = *(const v8bf*)&Pw[sz(l16, quad * 8)];
    v8bf p1 = *(const v8bf*)&Pw[sz(l16, 32 + quad * 8)];
    __builtin_amdgcn_s_setprio(1);
#pragma unroll
    for (int j = 0; j < 4; ++j) {
      v8bf vf0 = *(const v8bf*)&Vs[sz(j * 16 + l16, quad * 8)];
      v8bf vf1 = *(const v8bf*)&Vs[sz(j * 16 + l16, 32 + quad * 8)];
      O[j] = mfma16(p1, vf1, mfma16(p0, vf0, O[j]));
    }
    S = mfma16(p1, ones, mfma16(p0, ones, S));
    __builtin_amdgcn_s_setprio(0);
  }

#pragma unroll
  for (int r = 0; r < 4; ++r) {
    float inv = 1.0f / S[r];
    int row = b * 2048 + qf + quad * 4 + r;
    BF* op = out + (size_t)row * 768 + h * 64 + l16;
#pragma unroll
    for (int j = 0; j < 4; ++j) op[j * 16] = tob(O[j][r] * inv);
  }
}

extern "C" void kernel_launch(void* const* d_in, const int* in_sizes, int n_in,
                              void* d_out, int out_size, void* d_ws, size_t ws_size,
                              hipStream_t stream) {
  const float* x        = (const float*)d_in[0];
  const float* ln1_w    = (const float*)d_in[1];
  const float* ln1_b    = (const float*)d_in[2];
  const float* c_attn_w = (const float*)d_in[3];
  const float* c_attn_b = (const float*)d_in[4];
  const float* c_proj_w = (const float*)d_in[5];
  const float* c_proj_b = (const float*)d_in[6];
  const float* ln2_w    = (const float*)d_in[7];
  const float* ln2_b    = (const float*)d_in[8];
  const float* fc_w     = (const float*)d_in[9];
  const float* fc_b     = (const float*)d_in[10];
  const float* mproj_w  = (const float*)d_in[11];
  const float* mproj_b  = (const float*)d_in[12];
  float* out = (float*)d_out;
  char* wsb = (char*)d_ws;
  dim3 blk(256);

  BF* vT = (BF*)((char*)d_out + 12582912);

  const size_t NEED_BIG = 89653248;
  if (ws_size >= NEED_BIG) {
    BF* qkv      = (BF*)(wsb);
    BF* hbuf     = (BF*)(wsb);
    BF* x2       = (BF*)(wsb + 50331648);
    BF* wT_attn  = (BF*)(wsb + 62914560);
    BF* wT_proj  = (BF*)(wsb + 66453504);
    BF* wT_fc    = (BF*)(wsb + 67633152);
    BF* wT_mproj = (BF*)(wsb + 72351744);
    BF* lnbuf    = (BF*)(wsb + 77070336);
    BF* attnout  = (BF*)d_out;

    prep_k<<<dim3(9920), blk, 0, stream>>>(c_attn_w, wT_attn, c_proj_w, wT_proj,
                                           fc_w, wT_fc, mproj_w, wT_mproj,
                                           x, ln1_w, ln1_b, lnbuf);
    gemm_sm_k<128, 0, false, float, BF><<<dim3(18, 64), blk, 0, stream>>>(
        lnbuf, wT_attn, c_attn_b, (const float*)nullptr, qkv, 8192, 2304, 768);
    vtrans_k<<<dim3(32, 48), blk, 0, stream>>>(qkv, vT);
    attn_k<<<dim3(1536), blk, 0, stream>>>(qkv, vT, attnout);
    gemm_sm_k<64, 0, true, float, BF><<<dim3(12, 64), blk, 0, stream>>>(
        attnout, wT_proj, c_proj_b, x, x2, 8192, 768, 768);
    ln_k<BF><<<8192, blk, 0, stream>>>(x2, ln2_w, ln2_b, lnbuf);
    gemm64_k<1, false, float, BF><<<dim3(24, 128), blk, 0, stream>>>(
        lnbuf, wT_fc, fc_b, (const float*)nullptr, hbuf, 8192, 3072, 768);   // probe
    gemm_sm_k<64, 0, true, BF, float><<<dim3(12, 64), blk, 0, stream>>>(
        hbuf, wT_mproj, mproj_b, x2, out, 8192, 768, 3072);
  } else {
    BF* ws       = (BF*)d_ws;
    BF* qkv      = ws;
    BF* attnout  = ws + (size_t)18874368;
    BF* wT_attn  = attnout;
    BF* x2       = ws;
    BF* wT_proj  = ws + (size_t)6291456;
    BF* wT_fc    = ws + (size_t)6881280;
    BF* wT_mproj = ws + (size_t)9240576;
    BF* hbuf     = ws + (size_t)11599872;
    BF* lnbuf    = (BF*)d_out;

    transpose_k<<<dim3(36, 12), blk, 0, stream>>>(c_attn_w, wT_attn, 768, 2304);
    ln_k<float><<<8192, blk, 0, stream>>>(x, ln1_w, ln1_b, lnbuf);
    gemm_sm_k<128, 0, false, float, BF><<<dim3(18, 64), blk, 0, stream>>>(
        lnbuf, wT_attn, c_attn_b, (const float*)nullptr, qkv, 8192, 2304, 768);
    vtrans_k<<<dim3(32, 48), blk, 0, stream>>>(qkv, vT);
    attn_k<<<dim3(1536), blk, 0, stream>>>(qkv, vT, attnout);
    transpose_k<<<dim3(12, 12), blk, 0, stream>>>(c_proj_w, wT_proj, 768, 768);
    gemm_sm_k<64, 0, true, float, BF><<<dim3(12, 64), blk, 0, stream>>>(
        attnout, wT_proj, c_proj_b, x, x2, 8192, 768, 768);
    ln_k<BF><<<8192, blk, 0, stream>>>(x2, ln2_w, ln2_b, lnbuf);
    transpose_k<<<dim3(48, 12), blk, 0, stream>>>(fc_w, wT_fc, 768, 3072);
    transpose_k<<<dim3(12, 48), blk, 0, stream>>>(mproj_w, wT_mproj, 3072, 768);
    for (int half = 1; half >= 0; --half) {
      size_t r0 = (size_t)half * 4096;
      gemm_sm_k<128, 1, false, float, BF><<<dim3(24, 32), blk, 0, stream>>>(
          lnbuf + r0 * 768, wT_fc, fc_b, (const float*)nullptr, hbuf, 4096, 3072, 768);
      gemm_sm_k<64, 0, true, BF, float><<<dim3(12, 32), blk, 0, stream>>>(
          hbuf, wT_mproj, mproj_b, x2 + r0 * 768, out + r0 * 768, 4096, 768, 3072);
    }
  }
}